// Round 1
// baseline (82.446 us; speedup 1.0000x reference)
//
#include <hip/hip_runtime.h>

#define EPS 1e-6f

__global__ void zero_out_kernel(float* out) { out[0] = 0.0f; }

__global__ __launch_bounds__(256) void traj_loss_kernel(
    const float* __restrict__ anear,
    const float* __restrict__ afar,
    const int* __restrict__ na_idx,   // near_anchor_indexs (B,K)
    const int* __restrict__ fa_idx,   // far_anchor_indexs  (B,K)
    const int* __restrict__ ne_idx,   // near_indexs        (B,K)
    const int* __restrict__ fe_idx,   // far_indexs         (B,K)
    const float* __restrict__ ntgt,   // near_target (B*K)
    const float* __restrict__ ftgt,   // far_target  (B*K)
    float* __restrict__ out,
    int B, int K)
{
    // one 64-lane wave per (side, b, k) row; D = 128 -> float2 per lane
    const int gtid = blockIdx.x * blockDim.x + threadIdx.x;
    const int wave = gtid >> 6;
    const int lane = threadIdx.x & 63;
    const int BK = B * K;
    const int total = 2 * BK;
    if (wave >= total) return;

    const int side = (wave >= BK) ? 1 : 0;   // 0 = near, 1 = far
    const int row  = side ? (wave - BK) : wave;   // row = b*K + k
    const int b    = row / K;

    const float* src = side ? afar  : anear;
    const int*   ia  = side ? fa_idx : na_idx;
    const int*   ib  = side ? fe_idx : ne_idx;
    const float* tg  = side ? ftgt  : ntgt;

    const int sa = ia[row];
    const int sb = ib[row];

    // layout (S, B, D=128) row-major: elem (s,b,d) at ((s*B)+b)*128 + d
    const float2* pa = (const float2*)(src + ((size_t)sa * B + b) * 128);
    const float2* pb = (const float2*)(src + ((size_t)sb * B + b) * 128);

    const float2 va = pa[lane];
    const float2 vb = pb[lane];
    const float dx = va.x - vb.x + EPS;
    const float dy = va.y - vb.y + EPS;
    float s = dx * dx + dy * dy;

    // wave-wide sum (64 lanes)
    #pragma unroll
    for (int off = 32; off > 0; off >>= 1)
        s += __shfl_down(s, off, 64);

    if (lane == 0) {
        const float pred = __expf(-sqrtf(s));
        const float l = pred - tg[row];
        atomicAdd(out, l * l);
    }
}

extern "C" void kernel_launch(void* const* d_in, const int* in_sizes, int n_in,
                              void* d_out, int out_size, void* d_ws, size_t ws_size,
                              hipStream_t stream) {
    const float* anear = (const float*)d_in[0];
    const float* afar  = (const float*)d_in[1];
    const int* na_idx  = (const int*)d_in[2];
    const int* fa_idx  = (const int*)d_in[3];
    const int* ne_idx  = (const int*)d_in[4];
    const int* fe_idx  = (const int*)d_in[5];
    const float* ntgt  = (const float*)d_in[6];
    const float* ftgt  = (const float*)d_in[7];
    float* out = (float*)d_out;

    const int B = 256;
    const int K = 11;

    const int totalWaves = 2 * B * K;            // 5632 rows
    const int wavesPerBlock = 4;                 // 256 threads
    const int grid = (totalWaves + wavesPerBlock - 1) / wavesPerBlock;

    zero_out_kernel<<<1, 1, 0, stream>>>(out);
    traj_loss_kernel<<<grid, 256, 0, stream>>>(anear, afar, na_idx, fa_idx,
                                               ne_idx, fe_idx, ntgt, ftgt,
                                               out, B, K);
}

// Round 2
// 12.250 us; speedup vs baseline: 6.7300x; 6.7300x over previous
//
#include <hip/hip_runtime.h>

#define EPS 1e-6f

// ---------------- Kernel 1: per-row loss, one wave per (side,b,k) row ----------------
// 5632 rows, 4 waves/block -> 1408 blocks; each block writes ONE partial to ws.
__global__ __launch_bounds__(256) void traj_loss_partial_kernel(
    const float* __restrict__ anear,
    const float* __restrict__ afar,
    const int* __restrict__ na_idx,   // near_anchor_indexs (B,K)
    const int* __restrict__ fa_idx,   // far_anchor_indexs  (B,K)
    const int* __restrict__ ne_idx,   // near_indexs        (B,K)
    const int* __restrict__ fe_idx,   // far_indexs         (B,K)
    const float* __restrict__ ntgt,   // near_target (B*K)
    const float* __restrict__ ftgt,   // far_target  (B*K)
    float* __restrict__ partials,
    int B, int K)
{
    const int gtid = blockIdx.x * blockDim.x + threadIdx.x;
    const int wave = gtid >> 6;
    const int lane = threadIdx.x & 63;
    const int wid  = threadIdx.x >> 6;          // wave within block (0..3)
    const int BK = B * K;
    const int total = 2 * BK;

    __shared__ float warp_part[4];

    float loss2 = 0.0f;
    if (wave < total) {
        const int side = (wave >= BK) ? 1 : 0;      // 0 = near, 1 = far
        const int row  = side ? (wave - BK) : wave; // row = b*K + k
        const int b    = row / K;

        const float* src = side ? afar   : anear;
        const int*   ia  = side ? fa_idx : na_idx;
        const int*   ib  = side ? fe_idx : ne_idx;
        const float* tg  = side ? ftgt   : ntgt;

        const int sa = ia[row];
        const int sb = ib[row];

        // layout (S, B, D=128): elem (s,b,d) at ((s*B)+b)*128 + d
        const float2* pa = (const float2*)(src + ((size_t)sa * B + b) * 128);
        const float2* pb = (const float2*)(src + ((size_t)sb * B + b) * 128);

        const float2 va = pa[lane];
        const float2 vb = pb[lane];
        const float dx = va.x - vb.x + EPS;
        const float dy = va.y - vb.y + EPS;
        float s = dx * dx + dy * dy;

        #pragma unroll
        for (int off = 32; off > 0; off >>= 1)
            s += __shfl_down(s, off, 64);

        if (lane == 0) {
            const float pred = __expf(-sqrtf(s));
            const float l = pred - tg[row];
            loss2 = l * l;
        }
    }

    if (lane == 0) warp_part[wid] = loss2;
    __syncthreads();
    if (threadIdx.x == 0) {
        partials[blockIdx.x] = warp_part[0] + warp_part[1] + warp_part[2] + warp_part[3];
    }
}

// ---------------- Kernel 2: reduce 1408 partials -> out[0] (overwrite) ----------------
__global__ __launch_bounds__(256) void reduce_partials_kernel(
    const float* __restrict__ partials, float* __restrict__ out, int n)
{
    float s = 0.0f;
    for (int i = threadIdx.x; i < n; i += 256)
        s += partials[i];

    #pragma unroll
    for (int off = 32; off > 0; off >>= 1)
        s += __shfl_down(s, off, 64);

    __shared__ float warp_part[4];
    const int lane = threadIdx.x & 63;
    const int wid  = threadIdx.x >> 6;
    if (lane == 0) warp_part[wid] = s;
    __syncthreads();
    if (threadIdx.x == 0)
        out[0] = warp_part[0] + warp_part[1] + warp_part[2] + warp_part[3];
}

extern "C" void kernel_launch(void* const* d_in, const int* in_sizes, int n_in,
                              void* d_out, int out_size, void* d_ws, size_t ws_size,
                              hipStream_t stream) {
    const float* anear = (const float*)d_in[0];
    const float* afar  = (const float*)d_in[1];
    const int* na_idx  = (const int*)d_in[2];
    const int* fa_idx  = (const int*)d_in[3];
    const int* ne_idx  = (const int*)d_in[4];
    const int* fe_idx  = (const int*)d_in[5];
    const float* ntgt  = (const float*)d_in[6];
    const float* ftgt  = (const float*)d_in[7];
    float* out = (float*)d_out;
    float* partials = (float*)d_ws;

    const int B = 256;
    const int K = 11;

    const int totalWaves = 2 * B * K;            // 5632 rows
    const int wavesPerBlock = 4;                 // 256 threads
    const int grid = (totalWaves + wavesPerBlock - 1) / wavesPerBlock;  // 1408

    traj_loss_partial_kernel<<<grid, 256, 0, stream>>>(anear, afar, na_idx, fa_idx,
                                                       ne_idx, fe_idx, ntgt, ftgt,
                                                       partials, B, K);
    reduce_partials_kernel<<<1, 256, 0, stream>>>(partials, out, grid);
}